// Round 3
// baseline (100.809 us; speedup 1.0000x reference)
//
#include <hip/hip_runtime.h>
#include <math.h>

#define B_DIM 8
#define T_DIM 1024
#define D_DIM 512
#define BT (B_DIM * T_DIM)   // 8192
#define NTILE 64             // 16-row tiles per batch
#define NBLK_BAND (B_DIM * NTILE)   // 512

typedef __bf16 bf16x8 __attribute__((ext_vector_type(8)));
typedef float floatx4 __attribute__((ext_vector_type(4)));

__device__ __forceinline__ float wave_reduce_sum(float v) {
#pragma unroll
    for (int off = 32; off > 0; off >>= 1) v += __shfl_xor(v, off, 64);
    return v;
}

// fp32 -> bf16 round-to-nearest-even
__device__ __forceinline__ ushort f2bf(float x) {
    unsigned u = __float_as_uint(x);
    unsigned r = (u + 0x7fffu + ((u >> 16) & 1u)) >> 16;
    return (ushort)r;
}

__device__ __forceinline__ float softplus(float y) {
    // stable softplus(y) = max(y,0) + log1p(exp(-|y|))
    return fmaxf(y, 0.0f) + log1pf(expf(-fabsf(y)));
}

// ---------------- Phase 1: normalize + convert to bf16 ----------------
__global__ __launch_bounds__(256) void prep_kernel(
    const float* __restrict__ m, const float* __restrict__ a,
    ushort* __restrict__ mhat, ushort* __restrict__ ahat)
{
    int wid  = blockIdx.x * 4 + (threadIdx.x >> 6);   // row in [0, 8192)
    int lane = threadIdx.x & 63;
    const float4* mr = (const float4*)(m + (size_t)wid * D_DIM);
    const float4* ar = (const float4*)(a + (size_t)wid * D_DIM);
    float4 m0 = mr[lane], m1 = mr[lane + 64];
    float4 a0 = ar[lane], a1 = ar[lane + 64];
    float sm = m0.x*m0.x + m0.y*m0.y + m0.z*m0.z + m0.w*m0.w
             + m1.x*m1.x + m1.y*m1.y + m1.z*m1.z + m1.w*m1.w;
    float sa = a0.x*a0.x + a0.y*a0.y + a0.z*a0.z + a0.w*a0.w
             + a1.x*a1.x + a1.y*a1.y + a1.z*a1.z + a1.w*a1.w;
    sm = wave_reduce_sum(sm);
    sa = wave_reduce_sum(sa);
    float im = 1.0f / fmaxf(sqrtf(sm), 1e-12f);
    float ia = 1.0f / fmaxf(sqrtf(sa), 1e-12f);
    ushort4 mo0 = { f2bf(m0.x*im), f2bf(m0.y*im), f2bf(m0.z*im), f2bf(m0.w*im) };
    ushort4 mo1 = { f2bf(m1.x*im), f2bf(m1.y*im), f2bf(m1.z*im), f2bf(m1.w*im) };
    ushort4 ao0 = { f2bf(a0.x*ia), f2bf(a0.y*ia), f2bf(a0.z*ia), f2bf(a0.w*ia) };
    ushort4 ao1 = { f2bf(a1.x*ia), f2bf(a1.y*ia), f2bf(a1.z*ia), f2bf(a1.w*ia) };
    ushort4* mw = (ushort4*)(mhat + (size_t)wid * D_DIM);
    ushort4* aw = (ushort4*)(ahat + (size_t)wid * D_DIM);
    mw[lane] = mo0; mw[lane + 64] = mo1;
    aw[lane] = ao0; aw[lane + 64] = ao1;
}

// ---------------- Phase 2: banded Gram via MFMA + fused loss ----------------
// Block = (b, t0). Computes S[i][k] = mhat_{t0+i} . ahat_{t0-16+k}, i in [0,16),
// k in [0,48). Band diag index dd = k - i in [0,32] <-> c - t in [-16,16].
// Fused epilogue: loss terms for both directions, m2a per-row argmax (full),
// a2m per-column partial max over this block's 16 rows -> pm[].
__global__ __launch_bounds__(256) void bandloss_kernel(
    const ushort* __restrict__ mhat, const ushort* __restrict__ ahat,
    const float* __restrict__ pscale, const float* __restrict__ pbias,
    float2* __restrict__ pm,
    float* __restrict__ part_loss, float* __restrict__ part_corr)
{
    int blk = blockIdx.x;                 // 512 blocks
    int b   = blk >> 6;
    int t0  = (blk & 63) << 4;
    int tid  = threadIdx.x;
    int w    = tid >> 6;                  // wave id: k-split
    int lane = tid & 63;
    int mrow = lane & 15;                 // fragment row (m or n index)
    int kgrp = lane >> 4;                 // k-group within fragment

    const ushort* Abase = mhat + ((size_t)b << 19);   // b*1024*512
    const ushort* Bbase = ahat + ((size_t)b << 19);
    int koff = w * 128 + kgrp * 8;

    const ushort* arow = Abase + (size_t)(t0 + mrow) * D_DIM + koff;
    int j0 = max(t0 - 16 + mrow, 0);
    int j1 = t0 + mrow;
    int j2 = min(t0 + 16 + mrow, T_DIM - 1);
    const ushort* br0 = Bbase + (size_t)j0 * D_DIM + koff;
    const ushort* br1 = Bbase + (size_t)j1 * D_DIM + koff;
    const ushort* br2 = Bbase + (size_t)j2 * D_DIM + koff;

    floatx4 acc0 = {0.f,0.f,0.f,0.f};
    floatx4 acc1 = {0.f,0.f,0.f,0.f};
    floatx4 acc2 = {0.f,0.f,0.f,0.f};
#pragma unroll
    for (int ks = 0; ks < 4; ++ks) {
        bf16x8 af = *(const bf16x8*)(arow + ks * 32);
        bf16x8 b0 = *(const bf16x8*)(br0 + ks * 32);
        bf16x8 b1 = *(const bf16x8*)(br1 + ks * 32);
        bf16x8 b2 = *(const bf16x8*)(br2 + ks * 32);
        acc0 = __builtin_amdgcn_mfma_f32_16x16x32_bf16(af, b0, acc0, 0, 0, 0);
        acc1 = __builtin_amdgcn_mfma_f32_16x16x32_bf16(af, b1, acc1, 0, 0, 0);
        acc2 = __builtin_amdgcn_mfma_f32_16x16x32_bf16(af, b2, acc2, 0, 0, 0);
    }

    // cross-wave (k-split) reduction in LDS.
    // C layout: col = lane&15, row = (lane>>4)*4 + reg   [guide §3, m89]
    __shared__ float red[4][3][256];
#pragma unroll
    for (int r = 0; r < 4; ++r) {
        int rr = (kgrp * 4 + r) * 16 + mrow;
        red[w][0][rr] = acc0[r];
        red[w][1][rr] = acc1[r];
        red[w][2][rr] = acc2[r];
    }
    __syncthreads();

    int i  = tid >> 4;   // local row (t - t0)
    int cc = tid & 15;   // col within j-tile
    float s[3];
#pragma unroll
    for (int jt = 0; jt < 3; ++jt)
        s[jt] = red[0][jt][tid] + red[1][jt][tid]
              + red[2][jt][tid] + red[3][jt][tid];

    __shared__ float Sbuf[16][48];
#pragma unroll
    for (int jt = 0; jt < 3; ++jt)
        Sbuf[i][jt * 16 + cc] = s[jt];

    float scale = expf(pscale[0]), bias = pbias[0];
    float loss = 0.0f;
    float mmax = -1e30f, mpos = 0.0f;
#pragma unroll
    for (int jt = 0; jt < 3; ++jt) {
        int k  = jt * 16 + cc;
        int dd = k - i;                 // diag + 16
        int c  = t0 - 16 + k;
        bool cv = (c >= 0) && (c < T_DIM);
        if (cv && dd >= 0 && dd <= 32) {
            float logit = s[jt] * scale + bias;
            if (dd < 32) {              // m2a entry (diag in [-16,16))
                bool pos = (dd >= 12) && (dd <= 19);   // diag in [-4,3]
                loss += softplus(pos ? -logit : logit);
                if (s[jt] > mmax) { mmax = s[jt]; mpos = pos ? 1.0f : 0.0f; }
            }
            if (dd > 0) {               // a2m entry (diag in (-16,16])
                bool pos = (dd >= 13) && (dd <= 20);   // diag in [-3,4]
                loss += softplus(pos ? -logit : logit);
            }
        }
    }

    // m2a row max across the 16 cc-lanes (within quarter-wave)
#pragma unroll
    for (int off = 1; off < 16; off <<= 1) {
        float ov = __shfl_xor(mmax, off, 64);
        float op = __shfl_xor(mpos, off, 64);
        if (ov > mmax) { mmax = ov; mpos = op; }
    }
    __shared__ float rowpos[16];
    if (cc == 0) rowpos[i] = mpos;

    loss = wave_reduce_sum(loss);
    __shared__ float shl[4];
    if (lane == 0) shl[w] = loss;
    __syncthreads();

    // a2m per-column partial max over this block's rows
    if (tid < 48) {
        int k = tid;
        int c = t0 - 16 + k;
        float bv = -1e30f, bp = 0.0f;
        if (c >= 0 && c < T_DIM) {
            int ilo = max(0, k - 32), ihi = min(16, k);
            for (int ii = ilo; ii < ihi; ++ii) {      // ascending r
                float v = Sbuf[ii][k];
                if (v > bv) {
                    bv = v;
                    int dd = k - ii;
                    bp = (dd >= 13 && dd <= 20) ? 1.0f : 0.0f;
                }
            }
        }
        pm[blk * 48 + k] = make_float2(bv, bp);
    }
    if (tid == 0) {
        part_loss[blk] = shl[0] + shl[1] + shl[2] + shl[3];
        float cs = 0.0f;
        for (int r = 0; r < 16; ++r) cs += rowpos[r];
        part_corr[blk] = cs;
    }
}

// ---------------- Phase 3: combine partials -> out ----------------
__global__ __launch_bounds__(1024) void final2_kernel(
    const float2* __restrict__ pm,
    const float* __restrict__ part_loss, const float* __restrict__ part_corr,
    float* __restrict__ out)
{
    int tid = threadIdx.x;
    float corr = 0.0f, loss = 0.0f;

    // a2m argmax: combine <=3 block partials per column
    for (int x = tid; x < BT; x += 1024) {
        int b = x >> 10, c = x & 1023;
        int tc = c >> 4;
        float bv = -1e30f, bp = 0.0f;
#pragma unroll
        for (int dp = -1; dp <= 1; ++dp) {   // ascending r
            int p = tc + dp;
            if (p < 0 || p >= NTILE) continue;
            int k = c - (p << 4) + 16;
            float2 v = pm[((b << 6) + p) * 48 + k];
            if (v.x > bv) { bv = v.x; bp = v.y; }
        }
        corr += bp;
    }
    if (tid < NBLK_BAND) {
        loss = part_loss[tid];
        corr += part_corr[tid];
    }

    loss = wave_reduce_sum(loss);
    corr = wave_reduce_sum(corr);
    __shared__ float shl[16], shc[16];
    int wv = tid >> 6, lane = tid & 63;
    if (lane == 0) { shl[wv] = loss; shc[wv] = corr; }
    __syncthreads();
    if (tid == 0) {
        float L = 0.0f, C = 0.0f;
#pragma unroll
        for (int r = 0; r < 16; ++r) { L += shl[r]; C += shc[r]; }
        out[0] = L / 16384.0f;   // (m2a+a2m)/(2T), mean over B folded in
        out[1] = C / 16384.0f;   // (m2a+a2m)/(2*T*B)
    }
}

extern "C" void kernel_launch(void* const* d_in, const int* in_sizes, int n_in,
                              void* d_out, int out_size, void* d_ws, size_t ws_size,
                              hipStream_t stream)
{
    const float* m  = (const float*)d_in[0];
    const float* a  = (const float*)d_in[1];
    const float* ps = (const float*)d_in[2];
    const float* pb = (const float*)d_in[3];
    float* out = (float*)d_out;

    const size_t MHAT_ELEMS = (size_t)BT * D_DIM;      // ushorts
    ushort* mhat = (ushort*)d_ws;
    ushort* ahat = mhat + MHAT_ELEMS;
    float2* pmb  = (float2*)(ahat + MHAT_ELEMS);       // 512*48 float2
    float*  part_loss = (float*)(pmb + NBLK_BAND * 48);
    float*  part_corr = part_loss + NBLK_BAND;

    prep_kernel<<<BT / 4, 256, 0, stream>>>(m, a, mhat, ahat);
    bandloss_kernel<<<NBLK_BAND, 256, 0, stream>>>(mhat, ahat, ps, pb,
                                                   pmb, part_loss, part_corr);
    final2_kernel<<<1, 1024, 0, stream>>>(pmb, part_loss, part_corr, out);
}